// Round 1
// baseline (549.342 us; speedup 1.0000x reference)
//
#include <hip/hip_runtime.h>
#include <hip/hip_bf16.h>
#include <cstdint>
#include <cstddef>

typedef int v4i __attribute__((ext_vector_type(4)));

#define NH 32
#define HD 128
#define SEQ 1024
#define HID 4096
#define BB 2
#define BKB 128   // K-bytes per LDS tile

__device__ __forceinline__ signed char quant_i8(float x) {
    float r = rintf(x);                       // round-half-to-even, matches jnp.round
    r = fminf(fmaxf(r, -128.0f), 127.0f);
    return (signed char)r;
}

#define GLOAD_LDS16(g, l) \
    __builtin_amdgcn_global_load_lds((const __attribute__((address_space(1))) void*)(g), \
                                     (__attribute__((address_space(3))) void*)(l), 16, 0, 0)

// ---------------- pack int32 -> int8 (all 4 weights in one launch) ----------------
__global__ __launch_bounds__(256) void pack4_i8_kernel(
    const int* __restrict__ s0, const int* __restrict__ s1,
    const int* __restrict__ s2, const int* __restrict__ s3,
    signed char* __restrict__ d0, signed char* __restrict__ d1,
    signed char* __restrict__ d2, signed char* __restrict__ d3, int n4)
{
    int i = blockIdx.x * 256 + threadIdx.x;
    int which = i >> 22;                  // n4 = HID*HID/4 = 2^22 (compile-time)
    int idx = i & ((1 << 22) - 1);
    const int* src = (which == 0) ? s0 : (which == 1) ? s1 : (which == 2) ? s2 : s3;
    signed char* dst = (which == 0) ? d0 : (which == 1) ? d1 : (which == 2) ? d2 : d3;
    int4 v = ((const int4*)src)[idx];
    char4 c;
    c.x = (signed char)v.x; c.y = (signed char)v.y;
    c.z = (signed char)v.z; c.w = (signed char)v.w;
    ((char4*)dst)[idx] = c;
}

// ---------------- quantize hidden_states ----------------
__global__ __launch_bounds__(256) void quant_x_kernel(const float* __restrict__ src,
                                                      signed char* __restrict__ dst, int n4) {
    int i = blockIdx.x * 256 + threadIdx.x;
    if (i >= n4) return;
    float4 v = ((const float4*)src)[i];
    char4 c;
    c.x = quant_i8(v.x * 50.0f);
    c.y = quant_i8(v.y * 50.0f);
    c.z = quant_i8(v.z * 50.0f);
    c.w = quant_i8(v.w * 50.0f);
    ((char4*)dst)[i] = c;
}

// ---------------- int8 GEMM core (double-buffered LDS): C[m,n] = A.B^T ----------------
// 128x128 block tile, BK=128B, 2x32KB LDS buffers. Stage k0+1 right after the
// barrier, compute k0 -> vmcnt drain overlaps the MFMA section.
// Swizzle: chunk kc of row r lives at slot (kc + r) & 7 (full row, NOT r>>1):
// read slot = (ks*4 + quad + lm) & 7 -> every aligned 8-lane group covers all
// 8 bank-groups -> conflict-free ds_read_b128 (old r>>1 variant: 2 lanes/group
// -> 2x phase serialization, 1.26e7 SQ_LDS_BANK_CONFLICT cycles/dispatch).
template<bool F32OUT>
__device__ __forceinline__ void gemm_core_db(
    const signed char* __restrict__ A, const signed char* __restrict__ Bw,
    const void* __restrict__ bias, void* __restrict__ outp,
    int m0, int n0, int N, int K, float alpha, float beta)
{
    __shared__ __align__(16) signed char sA[2 * 128 * BKB];
    __shared__ __align__(16) signed char sB[2 * 128 * BKB];

    const int t    = threadIdx.x;
    const int w    = t >> 6;
    const int lane = t & 63;
    const int lm   = lane & 15;
    const int quad = lane >> 4;
    const int wm   = (w >> 1) * 64;
    const int wn   = (w & 1) * 64;

    // staging map: LDS is linear (global_load_lds requires it); the swizzle is
    // applied on the per-lane GLOBAL source address instead (guide m173 pattern)
    int srow[4], skc[4];
    #pragma unroll
    for (int p = 0; p < 4; p++) {
        int si = t + 256 * p;
        int row = si >> 3;
        srow[p] = row;
        skc[p] = ((si & 7) - row) & 7;
    }

    v4i acc[4][4] = {};

    // prologue: stage buffer 0
    #pragma unroll
    for (int p = 0; p < 4; p++) {
        GLOAD_LDS16(A  + (size_t)(m0 + srow[p]) * K + skc[p] * 16, sA + t * 16 + p * 4096);
        GLOAD_LDS16(Bw + (size_t)(n0 + srow[p]) * K + skc[p] * 16, sB + t * 16 + p * 4096);
    }

    int buf = 0;
    for (int k0 = 0; k0 < K; k0 += BKB) {
        __syncthreads();   // publish buf (vmcnt drain overlapped w/ prev compute)

        if (k0 + BKB < K) {
            int nb = buf ^ 1;
            #pragma unroll
            for (int p = 0; p < 4; p++) {
                GLOAD_LDS16(A  + (size_t)(m0 + srow[p]) * K + k0 + BKB + skc[p] * 16,
                            sA + nb * 16384 + t * 16 + p * 4096);
                GLOAD_LDS16(Bw + (size_t)(n0 + srow[p]) * K + k0 + BKB + skc[p] * 16,
                            sB + nb * 16384 + t * 16 + p * 4096);
            }
        }

        const signed char* pA = sA + buf * 16384;
        const signed char* pB = sB + buf * 16384;
        #pragma unroll
        for (int ks = 0; ks < 2; ks++) {
            const int slot = (ks * 4 + quad + lm) & 7;   // conflict-free slot
            v4i af[4], bf[4];
            #pragma unroll
            for (int i = 0; i < 4; i++) {
                int row = wm + 16 * i + lm;
                af[i] = *(const v4i*)(pA + row * BKB + slot * 16);
            }
            #pragma unroll
            for (int j = 0; j < 4; j++) {
                int row = wn + 16 * j + lm;
                bf[j] = *(const v4i*)(pB + row * BKB + slot * 16);
            }
            #pragma unroll
            for (int i = 0; i < 4; i++)
                #pragma unroll
                for (int j = 0; j < 4; j++)
                    acc[i][j] = __builtin_amdgcn_mfma_i32_16x16x64_i8(af[i], bf[j], acc[i][j], 0, 0, 0);
        }
        buf ^= 1;
    }

    const int orow = quad * 4;
    #pragma unroll
    for (int i = 0; i < 4; i++) {
        #pragma unroll
        for (int j = 0; j < 4; j++) {
            #pragma unroll
            for (int r = 0; r < 4; r++) {
                int row = m0 + wm + 16 * i + orow + r;
                int col = n0 + wn + 16 * j + lm;
                float v = (float)acc[i][j][r];
                if (F32OUT) {
                    ((float*)outp)[(size_t)row * N + col] = v * alpha + ((const float*)bias)[col];
                } else {
                    float q = v * alpha + (float)((const int*)bias)[col] * beta;
                    ((signed char*)outp)[(size_t)row * N + col] = quant_i8(q);
                }
            }
        }
    }
}

// fused Q/K/V projection.
// XCD-chunked remap: dispatch-linear id -> xcd = id&7 owns B-panels
// [xcd*12, xcd*12+12) split in 3 groups of 4 (2MB, L2-resident); within a
// group sweep n fastest then m -> each B panel is fetched once per XCD and
// L2-hit for the other 15 m-tiles (was: same panel read concurrently from 8
// different XCDs -> all traffic to L3, ~1.5 GB/dispatch).
__global__ __launch_bounds__(256) void gemm_qkv(
    const signed char* __restrict__ x8,
    const signed char* __restrict__ wq, const signed char* __restrict__ wk,
    const signed char* __restrict__ wv,
    const int* __restrict__ bq, const int* __restrict__ bk, const int* __restrict__ bv,
    signed char* __restrict__ q8, signed char* __restrict__ k8, signed char* __restrict__ v8)
{
    const int id  = blockIdx.x + 96 * blockIdx.y;  // 0..1535 dispatch-linear
    const int xcd = id & 7;
    const int j   = id >> 3;          // 0..191 within-XCD sequence
    const int g   = j >> 6;           // 0..2: group of 4 B-panels
    const int r   = j & 63;
    const int nb  = xcd * 12 + g * 4 + (r & 3);   // n-panel 0..95
    const int m0  = (r >> 2) * 128;
    const int which = nb >> 5;
    const int n0  = (nb & 31) * 128;
    const signed char* Bw = (which == 0) ? wq : (which == 1) ? wk : wv;
    const int* bias = (which == 0) ? bq : (which == 1) ? bk : bv;
    signed char* outp = (which == 0) ? q8 : (which == 1) ? k8 : v8;
    gemm_core_db<false>(x8, Bw, bias, outp, m0, n0, HID, HID, 0.004f, 2.0f);
}

// o-proj (same XCD chunking: 4 panels = 2MB per XCD, reused over 16 m-tiles)
__global__ __launch_bounds__(256) void gemm_o(
    const signed char* __restrict__ c8, const signed char* __restrict__ wo,
    const float* __restrict__ bo, float* __restrict__ outp)
{
    const int id  = blockIdx.x + 32 * blockIdx.y;  // 0..511
    const int xcd = id & 7;
    const int j   = id >> 3;                        // 0..63
    const int nb  = xcd * 4 + (j & 3);
    const int m0  = (j >> 2) * 128;
    gemm_core_db<true>(c8, wo, bo, outp, m0, nb * 128, HID, HID, 0.0005f, 0.0f);
}

// ---------------- RoPE (in-place on q,k) + V transpose (8 s-rows/thread) ----------------
__global__ __launch_bounds__(128) void rope_kernel(
    const int* __restrict__ pos_ids, signed char* __restrict__ q,
    signed char* __restrict__ k, const signed char* __restrict__ v,
    signed char* __restrict__ vt)
{
    const int bid = blockIdx.x;
    const int sg = bid & 127;
    const int h  = (bid >> 7) & (NH - 1);
    const int b  = bid >> 12;
    const int d  = threadIdx.x;
    const int s0 = sg * 8;
    const int bh = b * NH + h;

    float inv = expf(-(float)(2 * (d & 63)) * (9.210340371976184f / 128.0f));

    float qd[8], qp[8], kd[8], kp[8];
    signed char vd[8];
    int pos[8];
    size_t base[8];
    #pragma unroll
    for (int i = 0; i < 8; i++) {
        int s = s0 + i;
        base[i] = ((size_t)(b * SEQ + s) * NH + h) * (size_t)HD;
        pos[i] = pos_ids[b * SEQ + s];
        qd[i] = (float)q[base[i] + d];
        qp[i] = (float)q[base[i] + (d ^ 64)];
        kd[i] = (float)k[base[i] + d];
        kp[i] = (float)k[base[i] + (d ^ 64)];
        vd[i] = v[base[i] + d];
    }
    __syncthreads();

    union { signed char c[8]; int2 i2; } vu;
    #pragma unroll
    for (int i = 0; i < 8; i++) {
        float freq = (float)pos[i] * inv;
        float cs, sn;
        __sincosf(freq, &sn, &cs);    // fast HW sin/cos; |err| ~1e-4 << i8 quant step
        float rotq = (d < 64) ? -qp[i] : qp[i];
        float rotk = (d < 64) ? -kp[i] : kp[i];
        q[base[i] + d] = quant_i8(qd[i] * cs + rotq * sn);
        k[base[i] + d] = quant_i8(kd[i] * cs + rotk * sn);
        vu.c[i] = vd[i];
    }
    *(int2*)(vt + ((size_t)(bh * HD + d)) * SEQ + s0) = vu.i2;
}

// ---------------- attention: 32 q-rows/block, K/V frags reused for 2 row-sets ----------------
// P-buffer chunk swizzle: logical 16B-chunk c of row r lives at (c + 4*r) & 63.
// Phase-D read bank-group = (5*lm + quad + const) & 7 -> bijective over every
// aligned 8-lane group (was 4(lm+quad): 8 lanes per bank-group). Writes stay
// 2-way (free, m136).
__global__ __launch_bounds__(256) void attn_kernel(
    const signed char* __restrict__ q, const signed char* __restrict__ k,
    const signed char* __restrict__ vt, signed char* __restrict__ ctx)
{
    __shared__ __align__(16) signed char p8[32 * 1040];
    __shared__ float red[128];

    const int w    = threadIdx.x >> 6;
    const int lane = threadIdx.x & 63;
    const int bid  = blockIdx.x;
    const int mt   = bid & 31;            // 32 row-tiles of 32
    const int bh   = bid >> 5;
    const int b    = bh >> 5, h = bh & 31;
    const int m0   = mt * 32;
    const int lm   = lane & 15;
    const int quad = lane >> 4;

    const float SCALE = 0.0025f / 11.313708498984761f;  // S_Q*S_K/sqrt(HD)
    const float LOG2E = 1.4426950408889634f;

    // two Q-row groups as B-operands
    const signed char* qb_base = q + ((size_t)(b * SEQ + m0 + lm) * NH + h) * (size_t)HD + quad * 16;
    v4i qb0 = *(const v4i*)qb_base;
    v4i qb1 = *(const v4i*)(qb_base + 64);
    const signed char* qb_base2 = qb_base + (size_t)16 * NH * HD;
    v4i qb2 = *(const v4i*)qb_base2;
    v4i qb3 = *(const v4i*)(qb_base2 + 64);

    // ---- phase A: S^T tiles; each K-frag feeds both row-sets
    float vals0[16][4], vals1[16][4];
    #pragma unroll
    for (int j = 0; j < 16; j++) {
        int t0 = w * 256 + j * 16;
        const signed char* kb = k + ((size_t)(b * SEQ + t0 + lm) * NH + h) * (size_t)HD + quad * 16;
        v4i a0 = *(const v4i*)kb;
        v4i a1 = *(const v4i*)(kb + 64);
        v4i acc0 = {}, acc1 = {};
        __builtin_amdgcn_s_setprio(1);
        acc0 = __builtin_amdgcn_mfma_i32_16x16x64_i8(a0, qb0, acc0, 0, 0, 0);
        acc0 = __builtin_amdgcn_mfma_i32_16x16x64_i8(a1, qb1, acc0, 0, 0, 0);
        acc1 = __builtin_amdgcn_mfma_i32_16x16x64_i8(a0, qb2, acc1, 0, 0, 0);
        acc1 = __builtin_amdgcn_mfma_i32_16x16x64_i8(a1, qb3, acc1, 0, 0, 0);
        __builtin_amdgcn_s_setprio(0);
        #pragma unroll
        for (int r = 0; r < 4; r++) {
            vals0[j][r] = (float)acc0[r] * SCALE;
            vals1[j][r] = (float)acc1[r] * SCALE;
        }
    }

    // ---- phase B: softmax for both row-sets (row q = m0+lm / m0+16+lm)
    float mx0 = vals0[0][0], mx1 = vals1[0][0];
    #pragma unroll
    for (int j = 0; j < 16; j++)
        #pragma unroll
        for (int r = 0; r < 4; r++) {
            mx0 = fmaxf(mx0, vals0[j][r]);
            mx1 = fmaxf(mx1, vals1[j][r]);
        }
    mx0 = fmaxf(mx0, __shfl_xor(mx0, 16)); mx0 = fmaxf(mx0, __shfl_xor(mx0, 32));
    mx1 = fmaxf(mx1, __shfl_xor(mx1, 16)); mx1 = fmaxf(mx1, __shfl_xor(mx1, 32));
    if (lane < 16) { red[w * 16 + lane] = mx0; red[64 + w * 16 + lane] = mx1; }
    __syncthreads();
    mx0 = fmaxf(fmaxf(red[lm], red[16 + lm]), fmaxf(red[32 + lm], red[48 + lm]));
    mx1 = fmaxf(fmaxf(red[64 + lm], red[80 + lm]), fmaxf(red[96 + lm], red[112 + lm]));

    float sum0 = 0.f, sum1 = 0.f;
    #pragma unroll
    for (int j = 0; j < 16; j++)
        #pragma unroll
        for (int r = 0; r < 4; r++) {
            vals0[j][r] = exp2f((vals0[j][r] - mx0) * LOG2E); sum0 += vals0[j][r];
            vals1[j][r] = exp2f((vals1[j][r] - mx1) * LOG2E); sum1 += vals1[j][r];
        }
    sum0 += __shfl_xor(sum0, 16); sum0 += __shfl_xor(sum0, 32);
    sum1 += __shfl_xor(sum1, 16); sum1 += __shfl_xor(sum1, 32);
    __syncthreads();
    if (lane < 16) { red[w * 16 + lane] = sum0; red[64 + w * 16 + lane] = sum1; }
    __syncthreads();
    sum0 = (red[lm] + red[16 + lm]) + (red[32 + lm] + red[48 + lm]);
    sum1 = (red[64 + lm] + red[80 + lm]) + (red[96 + lm] + red[112 + lm]);
    float sf0 = 127.0f / sum0, sf1 = 127.0f / sum1;

    // ---- phase C: quantize + write P rows lm and 16+lm (chunk-swizzled)
    #pragma unroll
    for (int j = 0; j < 16; j++) {
        union { signed char cc[4]; int ii; } u0, u1;
        #pragma unroll
        for (int r = 0; r < 4; r++) {
            u0.cc[r] = quant_i8(vals0[j][r] * sf0);
            u1.cc[r] = quant_i8(vals1[j][r] * sf1);
        }
        int ch = (((w * 16 + j) + 4 * lm) & 63) * 16 + quad * 4;  // f(r)=4r; 4*(16+lm) === 4*lm mod 64
        *(int*)(p8 + lm * 1040 + ch) = u0.ii;
        *(int*)(p8 + (16 + lm) * 1040 + ch) = u1.ii;
    }
    __syncthreads();

    // ---- phase D: PV; each Vt frag feeds both row-sets
    v4i accp0[2] = {}, accp1[2] = {};
    for (int kk = 0; kk < SEQ; kk += 64) {
        int ph = (((kk >> 4) + quad) + 4 * lm) & 63;   // swizzled physical chunk
        v4i af0 = *(const v4i*)(p8 + lm * 1040 + ph * 16);
        v4i af1 = *(const v4i*)(p8 + (16 + lm) * 1040 + ph * 16);
        v4i vb0 = *(const v4i*)(vt + ((size_t)(bh * HD + w * 32 + lm)) * (size_t)SEQ + kk + quad * 16);
        v4i vb1 = *(const v4i*)(vt + ((size_t)(bh * HD + w * 32 + 16 + lm)) * (size_t)SEQ + kk + quad * 16);
        __builtin_amdgcn_s_setprio(1);
        accp0[0] = __builtin_amdgcn_mfma_i32_16x16x64_i8(af0, vb0, accp0[0], 0, 0, 0);
        accp1[0] = __builtin_amdgcn_mfma_i32_16x16x64_i8(af1, vb0, accp1[0], 0, 0, 0);
        accp0[1] = __builtin_amdgcn_mfma_i32_16x16x64_i8(af0, vb1, accp0[1], 0, 0, 0);
        accp1[1] = __builtin_amdgcn_mfma_i32_16x16x64_i8(af1, vb1, accp1[1], 0, 0, 0);
        __builtin_amdgcn_s_setprio(0);
    }
    #pragma unroll
    for (int j = 0; j < 2; j++) {
        #pragma unroll
        for (int r = 0; r < 4; r++) {
            int row = quad * 4 + r;
            int col = w * 32 + j * 16 + lm;
            ctx[((size_t)(b * SEQ + m0 + row) * NH + h) * (size_t)HD + col] =
                quant_i8((float)accp0[j][r] * (1.0f / 127.0f));
            ctx[((size_t)(b * SEQ + m0 + 16 + row) * NH + h) * (size_t)HD + col] =
                quant_i8((float)accp1[j][r] * (1.0f / 127.0f));
        }
    }
}

// ---------------- launch ----------------
extern "C" void kernel_launch(void* const* d_in, const int* in_sizes, int n_in,
                              void* d_out, int out_size, void* d_ws, size_t ws_size,
                              hipStream_t stream)
{
    const float* hidden = (const float*)d_in[0];
    const int* pos_ids  = (const int*)d_in[1];
    const int* w_q = (const int*)d_in[2];
    const int* w_k = (const int*)d_in[3];
    const int* w_v = (const int*)d_in[4];
    const int* w_o = (const int*)d_in[5];
    const int* b_q = (const int*)d_in[6];
    const int* b_k = (const int*)d_in[7];
    const int* b_v = (const int*)d_in[8];
    const float* b_o = (const float*)d_in[9];
    float* out = (float*)d_out;

    char* ws = (char*)d_ws;
    const size_t WSZ = (size_t)HID * HID;
    signed char* wq8 = (signed char*)ws;
    signed char* wk8 = wq8 + WSZ;
    signed char* wv8 = wk8 + WSZ;
    signed char* wo8 = wv8 + WSZ;
    signed char* x8  = wo8 + WSZ;
    const size_t ASZ = (size_t)BB * SEQ * HID;
    signed char* q8  = x8 + ASZ;
    signed char* k8  = q8 + ASZ;
    signed char* v8  = k8 + ASZ;
    signed char* vt8 = v8 + ASZ;
    signed char* c8  = vt8 + ASZ;

    int wn4 = HID * HID / 4;
    pack4_i8_kernel<<<4 * wn4 / 256, 256, 0, stream>>>(w_q, w_k, w_v, w_o,
                                                       wq8, wk8, wv8, wo8, wn4);
    int xn4 = (int)(ASZ / 4);
    quant_x_kernel<<<xn4 / 256, 256, 0, stream>>>(hidden, x8, xn4);

    gemm_qkv<<<dim3(96, 16), 256, 0, stream>>>(x8, wq8, wk8, wv8, b_q, b_k, b_v,
                                               q8, k8, v8);

    rope_kernel<<<BB * NH * (SEQ / 8), 128, 0, stream>>>(pos_ids, q8, k8, v8, vt8);
    attn_kernel<<<BB * NH * (SEQ / 32), 256, 0, stream>>>(q8, k8, vt8, c8);

    gemm_o<<<dim3(32, 16), 256, 0, stream>>>(c8, wo8, b_o, out);
}